// Round 5
// baseline (1026.337 us; speedup 1.0000x reference)
//
#include <hip/hip_runtime.h>

// VQ quantizer forward: double-buffered bf16-MFMA distance GEMM (one barrier
// per K-chunk) + exact fp32 candidate refinement.
// x (16,256,64,64) fp32, w (2048,256) fp32.
// d_out = 16,777,216 floats (quantized, (b,c,h,w)) + 1 float (latent loss).

typedef __attribute__((ext_vector_type(8))) short short8;  // 8 bf16 (4 VGPR)
typedef __attribute__((ext_vector_type(4))) float f32x4;   // MFMA C/D

#define GLOBAL_AS __attribute__((address_space(1)))
#define LOCAL_AS  __attribute__((address_space(3)))

constexpr int NE   = 2048;
constexpr int DIM  = 256;
constexpr int HW   = 4096;
constexpr int NTOT = 16777216;
constexpr int ROWS   = 64;      // spatial rows per block
constexpr int CHUNK  = 32;      // codes per chunk (16 KB staged, double-buffered)
constexpr int NCHUNK = NE / CHUNK;   // 64
constexpr int CAP    = 16;      // candidate capacity per row (overflow -> rescan)
constexpr float TAU   = 0.75f;  // collect window (covers bf16 err + key trunc)
constexpr float SLACK = 1.0f;   // refine-trigger window
constexpr float LOSS_SCALE = 0.25f / 16777216.0f;

__device__ __forceinline__ unsigned short f2bf(float f) {  // RNE fp32->bf16
    unsigned u = __builtin_bit_cast(unsigned, f);
    u += 0x7fffu + ((u >> 16) & 1u);
    return (unsigned short)(u >> 16);
}
// distances are biased positive (+||x||^2), so raw float bits are monotone.
__device__ __forceinline__ unsigned pack_dc(float d, int code) {
    return (__builtin_bit_cast(unsigned, d) & 0xFFFFF800u) | (unsigned)code;
}
__device__ __forceinline__ float unpack_d(unsigned k) {
    return __builtin_bit_cast(float, k & 0xFFFFF800u);
}

// Kernel 1: ||w||^2 + swizzled bf16 copy of w (16B units permuted so main
// kernel's ds_read_b128 A-frags are bank-uniform); zero loss slot.
__global__ __launch_bounds__(256) void prep_kernel(const float* __restrict__ w,
                                                   unsigned short* __restrict__ wbf,
                                                   float* __restrict__ w2,
                                                   float* __restrict__ loss_slot) {
    const int lane = threadIdx.x & 63;
    const int wv   = threadIdx.x >> 6;
    const int code = blockIdx.x * 4 + wv;
    float4 v = *reinterpret_cast<const float4*>(w + (size_t)code * DIM + lane * 4);
    float s = v.x * v.x + v.y * v.y + v.z * v.z + v.w * v.w;
#pragma unroll
    for (int off = 32; off > 0; off >>= 1) s += __shfl_down(s, off, 64);
    if (lane == 0) w2[code] = s;
    const int u = lane >> 1;                          // 16B unit index
    const int p = (u & 24) | ((u + (code & 15)) & 7); // swizzled position
    ushort4 u4;
    u4.x = f2bf(v.x); u4.y = f2bf(v.y); u4.z = f2bf(v.z); u4.w = f2bf(v.w);
    *reinterpret_cast<ushort4*>(wbf + (size_t)code * DIM + p * 8 + (lane & 1) * 4) = u4;
    if (blockIdx.x == 0 && threadIdx.x == 0) *loss_slot = 0.0f;
}

__global__ __launch_bounds__(256, 3) void vq_kernel(const float* __restrict__ x,
                                                    const float* __restrict__ wg,
                                                    const unsigned short* __restrict__ wbf,
                                                    const float* __restrict__ w2g,
                                                    float* __restrict__ out,
                                                    float* __restrict__ loss_slot) {
    // ubuf: phase1 = bf16 x-transpose [64][264]; main = 2x16KB w dbuf;
    // epilogue = fp32 codeword staging [32][257]
    __shared__ alignas(16) unsigned char ubuf[33792];
    __shared__ unsigned runmin[ROWS];     // packed (trunc bits | code), atomicMin
    __shared__ unsigned cand[ROWS * CAP];
    __shared__ unsigned cnt[ROWS];
    __shared__ float    dbest[ROWS];      // final ||q-x||^2 per row (for loss)
    __shared__ int      bestc[ROWS];
    __shared__ int      scnt[ROWS];
    __shared__ float    xn2[ROWS];        // per-row ||x||^2 (fp32 exact)

    const int tid = threadIdx.x;
    const int blk = blockIdx.x;
    const int b   = blk >> 6;             // 64 blocks per image
    const int hw0 = (blk & 63) << 6;
    const size_t base = (size_t)b * (DIM * HW) + hw0;

    const int wv    = tid >> 6;
    const int lane  = tid & 63;
    const int col   = lane & 15;
    const int quad  = lane >> 4;
    const int mt    = wv >> 1;            // m-tile (16-code half of chunk)
    const int rbase = (wv & 1) * 32;      // this wave's 32-row half

    if (tid < ROWS) { runmin[tid] = 0xFFFFFFFFu; cnt[tid] = 0u; xn2[tid] = 0.f; }
    __syncthreads();

    // ---- phase 1: x -> bf16 LDS transpose xbf[row][k], stride 264 ----
    unsigned short* xbf = (unsigned short*)ubuf;
    {
        const int r0 = (tid & 15) * 4;    // 4 rows via float4 over hw
        const int c0 = (tid >> 4) * 16;   // 16 channels
        float s0 = 0.f, s1 = 0.f, s2 = 0.f, s3 = 0.f;
#pragma unroll
        for (int half = 0; half < 2; ++half) {
            float4 v[8];
#pragma unroll
            for (int cc = 0; cc < 8; ++cc)
                v[cc] = *reinterpret_cast<const float4*>(
                    x + base + (size_t)(c0 + half * 8 + cc) * HW + r0);
#pragma unroll
            for (int e = 0; e < 4; ++e) {
                float ve[8] = {((const float*)&v[0])[e], ((const float*)&v[1])[e],
                               ((const float*)&v[2])[e], ((const float*)&v[3])[e],
                               ((const float*)&v[4])[e], ((const float*)&v[5])[e],
                               ((const float*)&v[6])[e], ((const float*)&v[7])[e]};
                short8 s8;
#pragma unroll
                for (int cc = 0; cc < 8; ++cc) s8[cc] = (short)f2bf(ve[cc]);
                *reinterpret_cast<short8*>(xbf + (size_t)(r0 + e) * 264 + c0 + half * 8) = s8;
                float acc = 0.f;
#pragma unroll
                for (int cc = 0; cc < 8; ++cc) acc = fmaf(ve[cc], ve[cc], acc);
                if (e == 0) s0 += acc; else if (e == 1) s1 += acc;
                else if (e == 2) s2 += acc; else s3 += acc;
            }
        }
        atomicAdd(&xn2[r0 + 0], s0); atomicAdd(&xn2[r0 + 1], s1);
        atomicAdd(&xn2[r0 + 2], s2); atomicAdd(&xn2[r0 + 3], s3);
    }
    __syncthreads();

    // ---- build register B-frags: bx[nt][kk] = x[k=kk*32+quad*8+j][rbase+nt*16+col] ----
    short8 bx[2][8];
#pragma unroll
    for (int nt = 0; nt < 2; ++nt) {
        const unsigned short* xr = xbf + (size_t)(rbase + nt * 16 + col) * 264;
#pragma unroll
        for (int kk = 0; kk < 8; ++kk)
            bx[nt][kk] = *reinterpret_cast<const short8*>(xr + kk * 32 + quad * 8);
    }
    float xn2r[2] = {0.f, 0.f};  // loaded after barrier below (xbf done)
    __syncthreads();             // xbf reads done; ubuf becomes DMA dbuf

    xn2r[0] = xn2[rbase + col];
    xn2r[1] = xn2[rbase + 16 + col];

    // double buffer: buf(i) = ubuf + (i&1)*16384 (no pointer array: LDS
    // addrspacecast in a static initializer does not compile on gfx950)
    // issue DMA for chunk 0 into buf0 (drained by first loop barrier)
#pragma unroll
    for (int it = 0; it < 4; ++it) {
        const unsigned short* g = wbf + it * 2048 + wv * 512 + lane * 8;
        __builtin_amdgcn_global_load_lds((const GLOBAL_AS unsigned int*)g,
                                         (LOCAL_AS unsigned int*)((unsigned short*)ubuf + it * 2048 + wv * 512),
                                         16, 0, 0);
    }

    const int clocal = mt * 16 + col;     // this lane's A-row within chunk
    for (int ch = 0; ch < NCHUNK; ++ch) {
        __syncthreads();                  // drains DMA(ch); protects buf reuse
        if (ch < NCHUNK - 1) {            // prefetch ch+1 over this chunk's compute
            const size_t so = (size_t)(ch + 1) * CHUNK * DIM;
            unsigned short* dst = (unsigned short*)(ubuf + (((ch + 1) & 1) << 14));
#pragma unroll
            for (int it = 0; it < 4; ++it) {
                const unsigned short* g = wbf + so + it * 2048 + wv * 512 + lane * 8;
                __builtin_amdgcn_global_load_lds((const GLOBAL_AS unsigned int*)g,
                                                 (LOCAL_AS unsigned int*)(dst + it * 2048 + wv * 512),
                                                 16, 0, 0);
            }
        }
        const int cb = ch * CHUNK;
        float4 w2v = *reinterpret_cast<const float4*>(w2g + cb + mt * 16 + quad * 4);
        const unsigned short* wch = (const unsigned short*)(ubuf + ((ch & 1) << 14));

        f32x4 acc[2] = {{0.f, 0.f, 0.f, 0.f}, {0.f, 0.f, 0.f, 0.f}};
#pragma unroll
        for (int kk = 0; kk < 8; ++kk) {
            const int u = kk * 4 + quad;
            const int p = (u & 24) | ((u + col) & 7);
            short8 aw = *reinterpret_cast<const short8*>(wch + clocal * DIM + p * 8);
            acc[0] = __builtin_amdgcn_mfma_f32_16x16x32_bf16(aw, bx[0][kk], acc[0], 0, 0, 0);
            acc[1] = __builtin_amdgcn_mfma_f32_16x16x32_bf16(aw, bx[1][kk], acc[1], 0, 0, 0);
        }
        const float w2a[4] = {w2v.x, w2v.y, w2v.z, w2v.w};
        float dd[2][4];
#pragma unroll
        for (int nt = 0; nt < 2; ++nt)
#pragma unroll
            for (int j = 0; j < 4; ++j)
                dd[nt][j] = fmaf(-2.f, acc[nt][j], w2a[j]) + xn2r[nt];  // = ||q-x||^2 > 0

        if (ch == 0) {                    // one-time seed of runmin
#pragma unroll
            for (int nt = 0; nt < 2; ++nt) {
                unsigned pk = 0xFFFFFFFFu;
#pragma unroll
                for (int j = 0; j < 4; ++j)
                    pk = min(pk, pack_dc(dd[nt][j], mt * 16 + quad * 4 + j));
                pk = min(pk, __shfl_xor(pk, 16, 64));
                pk = min(pk, __shfl_xor(pk, 32, 64));
                if (quad == 0) atomicMin(&runmin[rbase + nt * 16 + col], pk);
            }
            __syncthreads();
        }
#pragma unroll
        for (int nt = 0; nt < 2; ++nt) {
            const int row = rbase + nt * 16 + col;
            const float thr = unpack_d(runmin[row]) + TAU;
#pragma unroll
            for (int j = 0; j < 4; ++j) {
                if (dd[nt][j] < thr) {    // rare: records of min + tau-window
                    const unsigned pk = pack_dc(dd[nt][j], cb + mt * 16 + quad * 4 + j);
                    const unsigned slot = atomicAdd(&cnt[row], 1u);
                    if (slot < (unsigned)CAP) cand[row * CAP + slot] = pk;
                    atomicMin(&runmin[row], pk);
                }
            }
        }
    }
    __syncthreads();

    // ---- select: decide unambiguous rows; near-ties or overflow -> refine ----
    if (tid < ROWS) {
        const unsigned key = runmin[tid];
        const int   c1 = (int)(key & 0x7FFu);
        const float d1 = unpack_d(key);
        bestc[tid] = c1; dbest[tid] = d1;
        const unsigned n = cnt[tid];
        if (n > (unsigned)CAP) { scnt[tid] = -1; }
        else {
            const float thr = d1 + SLACK;
            int m = 0; bool have_c1 = false;
            for (unsigned t = 0; t < n; ++t) {
                const unsigned e = cand[tid * CAP + t];
                if (unpack_d(e) <= thr) {
                    const int code = (int)(e & 0x7FFu);
                    if (code == c1) have_c1 = true;
                    cand[tid * CAP + m++] = (unsigned)code;
                }
            }
            if (!have_c1) cand[tid * CAP + m++] = (unsigned)c1;
            scnt[tid] = (m >= 2) ? m : 0;
        }
    }
    __syncthreads();

    // ---- exact fp32 refinement (wave per row; round-1 numerics) ----
    for (int r = wv; r < ROWS; r += 4) {
        const int m = scnt[r];
        if (m == 0) continue;
        const size_t xb = base + r;
        const float xr0 = x[xb + (size_t)(4 * lane + 0) * HW];
        const float xr1 = x[xb + (size_t)(4 * lane + 1) * HW];
        const float xr2 = x[xb + (size_t)(4 * lane + 2) * HW];
        const float xr3 = x[xb + (size_t)(4 * lane + 3) * HW];
        float bd = 1e38f; int bc = 0;
        if (m > 0) {
            for (int t = 0; t < m; ++t) {
                const int code = (int)cand[r * CAP + t];
                float4 wv4 = *reinterpret_cast<const float4*>(wg + (size_t)code * DIM + lane * 4);
                float sum = xr0 * wv4.x + xr1 * wv4.y + xr2 * wv4.z + xr3 * wv4.w;
#pragma unroll
                for (int o = 1; o < 64; o <<= 1) sum += __shfl_xor(sum, o, 64);
                const float d = w2g[code] - 2.0f * sum;
                if (t == 0 || d < bd || (d == bd && code < bc)) { bd = d; bc = code; }
            }
        } else {                          // overflow fallback: exact full scan
            for (int code = 0; code < NE; ++code) {
                float4 wv4 = *reinterpret_cast<const float4*>(wg + (size_t)code * DIM + lane * 4);
                float sum = xr0 * wv4.x + xr1 * wv4.y + xr2 * wv4.z + xr3 * wv4.w;
#pragma unroll
                for (int o = 1; o < 64; o <<= 1) sum += __shfl_xor(sum, o, 64);
                const float d = w2g[code] - 2.0f * sum;
                if (code == 0 || d < bd) { bd = d; bc = code; }
            }
        }
        if (lane == 0) { bestc[r] = bc; dbest[r] = bd + xn2[r]; }
    }
    __syncthreads();

    // ---- loss: sum_r ||q-x||^2 (dbest already includes ||x||^2) ----
    if (tid == 0) {
        float ls = 0.f;
        for (int r = 0; r < ROWS; ++r) ls += dbest[r];
        atomicAdd(loss_slot, ls * LOSS_SCALE);
    }

    // ---- epilogue: 2 passes x 32 rows; stride-257 staging, 128B store runs ----
    float* wst = (float*)ubuf;            // [32][257]
    const int rl = tid >> 3;
    const int tt = tid & 7;
    for (int h = 0; h < 2; ++h) {
        __syncthreads();
        const float* wrow = wg + (size_t)bestc[h * 32 + rl] * DIM;
#pragma unroll
        for (int it = 0; it < 8; ++it) {
            const int c4 = it * 8 + tt;
            float4 v = *reinterpret_cast<const float4*>(wrow + c4 * 4);
            float* d = wst + rl * 257 + c4 * 4;
            d[0] = v.x; d[1] = v.y; d[2] = v.z; d[3] = v.w;
        }
        __syncthreads();
#pragma unroll 4
        for (int it = 0; it < 32; ++it) {
            const int l = it * 256 + tid;
            const int i = l & 31, c = l >> 5;
            out[base + (size_t)c * HW + h * 32 + i] = wst[i * 257 + c];
        }
    }
}

extern "C" void kernel_launch(void* const* d_in, const int* in_sizes, int n_in,
                              void* d_out, int out_size, void* d_ws, size_t ws_size,
                              hipStream_t stream) {
    const float* x = (const float*)d_in[0];
    const float* w = (const float*)d_in[1];
    float* out       = (float*)d_out;
    float* loss_slot = out + NTOT;
    unsigned short* wbf = (unsigned short*)d_ws;   // 1 MB swizzled bf16 w
    float* w2 = (float*)((char*)d_ws + (size_t)NE * DIM * sizeof(unsigned short));

    prep_kernel<<<NE / 4, 256, 0, stream>>>(w, wbf, w2, loss_slot);
    vq_kernel<<<65536 / ROWS, 256, 0, stream>>>(x, w, wbf, w2, out, loss_slot);
}